// Round 10
// baseline (30.743 us; speedup 1.0000x reference)
//
#include <hip/hip_runtime.h>
#include <math.h>

#define N_ANCH 87296
#define NCLS 91
#define NBINS 4096
#define K_CAND 256
#define K_SAMP 8
#define CAP 512
#define MAX_OUT 100
#define IOU_TH 0.6f
#define NB1 682
#define BT1 128
#define T2 1024          // K2 threads (16 waves)
#define NB16 10912       // N_ANCH*2B / 16B = uint4 count of bin array

// ws layout (bytes):
//        0: bins  (N_ANCH*2 = 174592)  u16 bin index per anchor
//   174592: pbox  (N_ANCH*16 = 1396736)  ends 1571328   (16B aligned)
//  1571328: pmeta (N_ANCH*16 = 1396736)  {area, label, score, 0}
// no memset required: every cell consumed is written by K1 first.

__device__ __forceinline__ float sigmoidf_(float x) {
    return 1.0f / (1.0f + expf(-x));
}

// Suffix-scan threshold find over a 4096-bin LDS hist. Call with the full
// first wave (tid<64). Writes to *s_dst from the crossing lane. Verified
// logic (r7-r9): lane l owns bins [l*64,(l+1)*64); shfl_down suffix scan;
// ballot+clz -> crossing lane; in-register descending refine.
__device__ __forceinline__ void scan_thresh(const unsigned* hist, int lane,
                                            unsigned K, int* s_dst) {
    const uint4* h4 = (const uint4*)hist;       // 1024 uint4
    uint4 c[16];
    #pragma unroll
    for (int q = 0; q < 16; ++q) c[q] = h4[lane * 16 + q];

    unsigned local = 0;
    #pragma unroll
    for (int q = 0; q < 16; ++q) local += c[q].x + c[q].y + c[q].z + c[q].w;

    unsigned p = local;                          // suffix-inclusive scan
    #pragma unroll
    for (int d = 1; d < 64; d <<= 1) {
        unsigned t = (unsigned)__shfl_down((int)p, d, 64);
        if (lane + d < 64) p += t;
    }
    unsigned long long mask = __ballot(p >= K);
    int L = 63 - __clzll(mask);
    unsigned sufAbove = (unsigned)__shfl((int)p, L + 1, 64);
    if (L == 63) sufAbove = 0u;

    if (lane == L) {
        unsigned cum = sufAbove;
        int fb = L * 64;
        bool found = false;
        #pragma unroll
        for (int q = 15; q >= 0; --q) {          // descending bins: w,z,y,x
            cum += c[q].w; if (!found && cum >= K) { fb = L * 64 + q * 4 + 3; found = true; }
            cum += c[q].z; if (!found && cum >= K) { fb = L * 64 + q * 4 + 2; found = true; }
            cum += c[q].y; if (!found && cum >= K) { fb = L * 64 + q * 4 + 1; found = true; }
            cum += c[q].x; if (!found && cum >= K) { fb = L * 64 + q * 4 + 0; found = true; }
        }
        *s_dst = fb;
    }
}

// K1: per-anchor score + label + box decode. Staging via
// __builtin_amdgcn_global_load_lds width=16 (no VGPR round-trip), wave-private
// A/B double buffer, counted vmcnt(6) so next chunk's HBM latency hides under
// the current chunk's reduce. No barriers (wave-private LDS). Reduce is the
// verified r9 quarter-row + shfl_xor(16,32) combine (first-max tie rule).
__global__ void __launch_bounds__(BT1, 2)
score_decode_kernel(const float* __restrict__ logits,
                    const float* __restrict__ boxreg,
                    const float* __restrict__ ctr,
                    const float* __restrict__ anchors,
                    unsigned short* __restrict__ bins,
                    float4* __restrict__ pbox,
                    float4* __restrict__ pmeta) {
    __shared__ __align__(16) float pool[2 * 2 * 1456];   // 23296 B
    const int tid  = threadIdx.x;
    const int lane = tid & 63;
    const int w    = tid >> 6;
    const int bid  = blockIdx.x;
    const int wavebase = bid * BT1 + w * 64;

    float* bufA = pool + w * 2912;
    float* bufB = bufA + 1456;

    const float4* g4 = (const float4*)logits + (size_t)wavebase * 91 / 4;

    // chunk c = 16 rows = 1456 floats = 364 float4; 6 gload_lds instrs/chunk
#define STAGE(buf, c) do {                                                   \
        const float4* gs_ = g4 + (c) * 364;                                  \
        _Pragma("unroll")                                                    \
        for (int k_ = 0; k_ < 6; ++k_) {                                     \
            int idx_ = k_ * 64 + lane;                                       \
            if (idx_ < 364) {                                                \
                __builtin_amdgcn_global_load_lds(                            \
                    (const __attribute__((address_space(1))) void*)(gs_ + idx_), \
                    (__attribute__((address_space(3))) void*)((buf) + k_ * 256), \
                    16, 0, 0);                                               \
            }                                                                \
        }                                                                    \
    } while (0)

    const int r  = lane & 15;            // local row within a chunk
    const int q  = lane >> 4;            // column quarter
    const int q0 = q * 23;
    const int qn = (q == 3) ? 22 : 23;   // [0,23)[23,46)[46,69)[69,91)

    float m = -INFINITY;
    int   lab = 0;

#define REDUCE(buf, c) do {                                                  \
        const float* rp_ = (buf) + r * 91 + q0;                              \
        float cm_ = rp_[0];                                                  \
        int   ci_ = q0;                                                      \
        _Pragma("unroll")                                                    \
        for (int j_ = 1; j_ < 23; ++j_) {                                    \
            if (j_ < qn) {                                                   \
                float v_ = rp_[j_];                                          \
                if (v_ > cm_) { cm_ = v_; ci_ = q0 + j_; }                   \
            }                                                                \
        }                                                                    \
        float om_ = __shfl_xor(cm_, 16, 64);                                 \
        int   oi_ = __shfl_xor(ci_, 16, 64);                                 \
        if (om_ > cm_ || (om_ == cm_ && oi_ < ci_)) { cm_ = om_; ci_ = oi_; }\
        om_ = __shfl_xor(cm_, 32, 64);                                       \
        oi_ = __shfl_xor(ci_, 32, 64);                                       \
        if (om_ > cm_ || (om_ == cm_ && oi_ < ci_)) { cm_ = om_; ci_ = oi_; }\
        if ((c) == q) { m = cm_; lab = ci_; }                                \
    } while (0)

    STAGE(bufA, 0);
    STAGE(bufB, 1);
    asm volatile("s_waitcnt vmcnt(6)" ::: "memory");   // A(c0) landed
    REDUCE(bufA, 0);
    asm volatile("s_waitcnt lgkmcnt(0)" ::: "memory"); // reads done before overwrite
    STAGE(bufA, 2);
    asm volatile("s_waitcnt vmcnt(6)" ::: "memory");   // B(c1) landed
    REDUCE(bufB, 1);
    asm volatile("s_waitcnt lgkmcnt(0)" ::: "memory");
    STAGE(bufB, 3);
    asm volatile("s_waitcnt vmcnt(6)" ::: "memory");   // A(c2) landed
    REDUCE(bufA, 2);
    asm volatile("s_waitcnt vmcnt(0)" ::: "memory");   // B(c3) landed
    REDUCE(bufB, 3);
#undef STAGE
#undef REDUCE

    const int i = wavebase + lane;
    const float s = sqrtf(sigmoidf_(m) * sigmoidf_(ctr[i]));
    const int bin = min(max((int)(s * (float)NBINS), 0), NBINS - 1);
    bins[i] = (unsigned short)bin;

    float4 A = ((const float4*)anchors)[i];
    float4 R = ((const float4*)boxreg)[i];
    float cx = 0.5f * (A.x + A.z);
    float cy = 0.5f * (A.y + A.w);
    float ww = A.z - A.x;
    float hh = A.w - A.y;
    float4 bb;
    bb.x = cx - R.x * ww;
    bb.y = cy - R.y * hh;
    bb.z = cx + R.z * ww;
    bb.w = cy + R.w * hh;
    pbox[i] = bb;
    float4 mt;
    mt.x = fmaxf(bb.z - bb.x, 0.0f) * fmaxf(bb.w - bb.y, 0.0f);
    mt.y = (float)lab;
    mt.z = s;
    mt.w = 0.0f;
    pmeta[i] = mt;
}

// K2: single WG. Bins -> registers once. Sampled prefilter: hist every 64th
// anchor (1.4K atomics) -> T_lo (sampled suffix >= 8) -> exact hist only for
// bins >= T_lo (~0.5-2K atomics instead of 87K). Exactness: for bins >= T_lo
// the filtered hist equals the full hist, and the K_CAND crossing lies in
// that range iff filtered-count >= K_CAND (checked; deterministic fallback
// completes the hist otherwise). Then verified compact/gather/NMS (NaN-lock).
__global__ void __launch_bounds__(T2)
select_nms_kernel(const unsigned short* __restrict__ bins,
                  const float4* __restrict__ pbox,
                  const float4* __restrict__ pmeta,
                  float* __restrict__ out) {
    __shared__ unsigned hist[NBINS];     // 16 KB
    __shared__ int      lidx[CAP];
    __shared__ unsigned cnt;
    __shared__ int      s_tlo, s_fb;
    __shared__ unsigned s_nf[16];
    __shared__ float    s_best[16];
    __shared__ int      s_bid[16];
    __shared__ float    s_box[5];
    __shared__ int      s_lab;

    const int tid  = threadIdx.x;
    const int lane = tid & 63;
    const int wid  = tid >> 6;

    for (int b = tid; b < NBINS; b += T2) hist[b] = 0u;
    if (tid == 0) cnt = 0u;

    // ---- single global read: bins -> registers ----
    const uint4* b4 = (const uint4*)bins;   // NB16 uint4
    uint4 bv[11];
    #pragma unroll
    for (int k = 0; k < 11; ++k) {
        int idx = k * T2 + tid;
        if (idx < NB16) {
            bv[k] = b4[idx];
        } else {
            uint4 z; z.x = z.y = z.z = z.w = 0u;   // bin 0 sentinel: inert
            bv[k] = z;
        }
    }
    __syncthreads();

    // ---- sample hist: anchors == 0 mod 64 (uint4 idx % 8 == 0, first u16) --
    #pragma unroll
    for (int k = 0; k < 11; ++k) {
        int idx = k * T2 + tid;
        if (idx < NB16 && (idx & 7) == 0)
            atomicAdd(&hist[bv[k].x & 0xFFFFu], 1u);
    }
    __syncthreads();
    if (tid < 64) scan_thresh(hist, lane, K_SAMP, &s_tlo);
    __syncthreads();
    const unsigned TLO = (unsigned)s_tlo;

    // ---- re-zero hist ----
    for (int b = tid; b < NBINS; b += T2) hist[b] = 0u;
    __syncthreads();

    // ---- filtered exact hist + count ----
    unsigned nf = 0;
    #pragma unroll
    for (int k = 0; k < 11; ++k) {
        int idx = k * T2 + tid;
        if (idx < NB16) {
            unsigned vv[4] = {bv[k].x, bv[k].y, bv[k].z, bv[k].w};
            #pragma unroll
            for (int j = 0; j < 4; ++j) {
                unsigned lo = vv[j] & 0xFFFFu;
                unsigned hi = vv[j] >> 16;
                if (lo >= TLO) { atomicAdd(&hist[lo], 1u); ++nf; }
                if (hi >= TLO) { atomicAdd(&hist[hi], 1u); ++nf; }
            }
        }
    }
    #pragma unroll
    for (int d = 32; d >= 1; d >>= 1)
        nf += (unsigned)__shfl_down((int)nf, d, 64);
    if (lane == 0) s_nf[wid] = nf;
    __syncthreads();
    unsigned NF = 0;
    #pragma unroll
    for (int ww = 0; ww < 16; ++ww) NF += s_nf[ww];   // uniform across block

    if (NF < K_CAND) {   // deterministic fallback: complete to the full hist
        #pragma unroll
        for (int k = 0; k < 11; ++k) {
            int idx = k * T2 + tid;
            if (idx < NB16) {
                unsigned vv[4] = {bv[k].x, bv[k].y, bv[k].z, bv[k].w};
                #pragma unroll
                for (int j = 0; j < 4; ++j) {
                    unsigned lo = vv[j] & 0xFFFFu;
                    unsigned hi = vv[j] >> 16;
                    if (lo < TLO) atomicAdd(&hist[lo], 1u);
                    if (hi < TLO) atomicAdd(&hist[hi], 1u);
                }
            }
        }
    }
    __syncthreads();
    if (tid < 64) scan_thresh(hist, lane, K_CAND, &s_fb);
    __syncthreads();
    const unsigned FB = (unsigned)s_fb;

    // ---- compact from registers ----
    #pragma unroll
    for (int k = 0; k < 11; ++k) {
        int idx = k * T2 + tid;
        if (idx < NB16) {
            unsigned vv[4] = {bv[k].x, bv[k].y, bv[k].z, bv[k].w};
            #pragma unroll
            for (int j = 0; j < 4; ++j) {
                unsigned lo = vv[j] & 0xFFFFu;
                unsigned hi = vv[j] >> 16;
                if (lo >= FB) {
                    unsigned pos = atomicAdd(&cnt, 1u);
                    if (pos < CAP) lidx[pos] = idx * 8 + 2 * j;
                }
                if (hi >= FB) {
                    unsigned pos = atomicAdd(&cnt, 1u);
                    if (pos < CAP) lidx[pos] = idx * 8 + 2 * j + 1;
                }
            }
        }
    }
    __syncthreads();
    const int M = (int)min(cnt, (unsigned)CAP);

    // ---- gather precomputed decode: thread t < M owns candidate t ----
    float SC, X1, Y1, X2, Y2, AR;
    int LAB;
    if (tid < M) {
        int ai = lidx[tid];
        float4 bb = pbox[ai];
        float4 mt = pmeta[ai];
        X1 = bb.x; Y1 = bb.y; X2 = bb.z; Y2 = bb.w;
        AR = mt.x;
        LAB = (int)mt.y;
        SC = mt.z;
    } else {
        SC = -INFINITY;
        X1 = Y1 = X2 = Y2 = AR = 0.0f;
        LAB = 0;
    }
    __syncthreads();

    // ---- greedy NMS (verified register version, 16-wave argmax) ----
    for (int it = 0; it < MAX_OUT; ++it) {
        float b = SC;
        int id = tid;
        #pragma unroll
        for (int d = 32; d >= 1; d >>= 1) {
            float ob = __shfl_xor(b, d, 64);
            int   oid = __shfl_xor(id, d, 64);
            if (ob > b) { b = ob; id = oid; }
        }
        if (lane == 0) { s_best[wid] = b; s_bid[wid] = id; }
        __syncthreads();
        float gb = s_best[0];
        int gid = s_bid[0];
        #pragma unroll
        for (int w = 1; w < 16; ++w) {
            if (s_best[w] > gb) { gb = s_best[w]; gid = s_bid[w]; }
        }
        if (tid == gid) {
            s_box[0] = X1; s_box[1] = Y1; s_box[2] = X2; s_box[3] = Y2;
            s_box[4] = AR; s_lab = LAB;
        }
        __syncthreads();
        float sx1 = s_box[0], sy1 = s_box[1], sx2 = s_box[2], sy2 = s_box[3];
        float sar = s_box[4];
        int   slab = s_lab;

        if (tid == 0) {
            out[it * 4 + 0] = sx1;
            out[it * 4 + 1] = sy1;
            out[it * 4 + 2] = sx2;
            out[it * 4 + 3] = sy2;
            out[4 * MAX_OUT + it] = (float)slab;
            out[5 * MAX_OUT + it] = gb;
        }

        // Lock: zero-area winner -> inter==0 with every box, self-iou=0/0=NaN,
        // NaN>0.6 false -> nothing suppressed -> reference re-selects this
        // same box for every remaining slot.
        if (sar == 0.0f) {
            for (int r = it + 1 + tid; r < MAX_OUT; r += T2) {
                out[r * 4 + 0] = sx1;
                out[r * 4 + 1] = sy1;
                out[r * 4 + 2] = sx2;
                out[r * 4 + 3] = sy2;
                out[4 * MAX_OUT + r] = (float)slab;
                out[5 * MAX_OUT + r] = gb;
            }
            return;
        }

        float ix1 = fmaxf(sx1, X1);
        float iy1 = fmaxf(sy1, Y1);
        float ix2 = fminf(sx2, X2);
        float iy2 = fminf(sy2, Y2);
        float inter = fmaxf(ix2 - ix1, 0.0f) * fmaxf(iy2 - iy1, 0.0f);
        float iou = inter / (sar + AR - inter);
        if (iou > IOU_TH) SC = -INFINITY;
        __syncthreads();
    }
}

extern "C" void kernel_launch(void* const* d_in, const int* in_sizes, int n_in,
                              void* d_out, int out_size, void* d_ws, size_t ws_size,
                              hipStream_t stream) {
    const float* logits  = (const float*)d_in[0];
    const float* boxreg  = (const float*)d_in[1];
    const float* ctr     = (const float*)d_in[2];
    const float* anchors = (const float*)d_in[3];
    float* out = (float*)d_out;

    char* ws = (char*)d_ws;
    unsigned short* bins = (unsigned short*)(ws + 0);
    float4*         pbox = (float4*)(ws + 174592);
    float4*         pmeta= (float4*)(ws + 1571328);

    score_decode_kernel<<<NB1, BT1, 0, stream>>>(logits, boxreg, ctr, anchors,
                                                 bins, pbox, pmeta);
    select_nms_kernel<<<1, T2, 0, stream>>>(bins, pbox, pmeta, out);
}